// Round 2
// 1858.244 us; speedup vs baseline: 1.3851x; 1.3851x over previous
//
#include <hip/hip_runtime.h>
#include <math.h>

#define NB 16
#define T  2048
#define D  512
#define BD 64
#define BT (NB*T)  // 32768

// workspace layout (float offsets)
#define OFF_K   0
#define OFF_V   (BT*BD)
#define OFF_Q   (2*BT*BD)
#define OFF_ETA (3*BT*BD)
#define OFF_H   (3*BT*BD + BT)
// total floats = 4*BT*BD + BT = 8,421,376  (~33.7 MB)

// ---------------- DPP full-wave sum, result broadcast to all lanes ----------
__device__ __forceinline__ float wave_allsum(float x) {
  x += __int_as_float(__builtin_amdgcn_update_dpp(
      0, __float_as_int(x), 0x111, 0xf, 0xf, true));   // row_shr:1
  x += __int_as_float(__builtin_amdgcn_update_dpp(
      0, __float_as_int(x), 0x112, 0xf, 0xf, true));   // row_shr:2
  x += __int_as_float(__builtin_amdgcn_update_dpp(
      0, __float_as_int(x), 0x114, 0xf, 0xf, true));   // row_shr:4
  x += __int_as_float(__builtin_amdgcn_update_dpp(
      0, __float_as_int(x), 0x118, 0xf, 0xf, true));   // row_shr:8
  x += __int_as_float(__builtin_amdgcn_update_dpp(
      0, __float_as_int(x), 0x142, 0xa, 0xf, false));  // row_bcast:15 -> rows 1,3
  x += __int_as_float(__builtin_amdgcn_update_dpp(
      0, __float_as_int(x), 0x143, 0xc, 0xf, false));  // row_bcast:31 -> rows 2,3
  return __int_as_float(__builtin_amdgcn_readlane(__float_as_int(x), 63));
}

// ---------------- projection: K,V,Q = x @ W{k,v,q} + b ----------------
__device__ __forceinline__ void do_proj(const float* __restrict__ W,
                                        const float* __restrict__ bias,
                                        float* __restrict__ Out,
                                        const float* xs, int col, int rg,
                                        size_t row0) {
  float a0 = 0.f, a1 = 0.f, a2 = 0.f, a3 = 0.f;
  for (int d = 0; d < D; d += 4) {
    float w0 = W[(d + 0) * BD + col];
    float w1 = W[(d + 1) * BD + col];
    float w2 = W[(d + 2) * BD + col];
    float w3 = W[(d + 3) * BD + col];
    const float* xb = xs + (rg * 4) * D + d;
    float4 x0 = *(const float4*)(xb);
    float4 x1 = *(const float4*)(xb + D);
    float4 x2 = *(const float4*)(xb + 2 * D);
    float4 x3 = *(const float4*)(xb + 3 * D);
    a0 += x0.x * w0 + x0.y * w1 + x0.z * w2 + x0.w * w3;
    a1 += x1.x * w0 + x1.y * w1 + x1.z * w2 + x1.w * w3;
    a2 += x2.x * w0 + x2.y * w1 + x2.z * w2 + x2.w * w3;
    a3 += x3.x * w0 + x3.y * w1 + x3.z * w2 + x3.w * w3;
  }
  float bb = bias[col];
  Out[(row0 + rg * 4 + 0) * BD + col] = a0 + bb;
  Out[(row0 + rg * 4 + 1) * BD + col] = a1 + bb;
  Out[(row0 + rg * 4 + 2) * BD + col] = a2 + bb;
  Out[(row0 + rg * 4 + 3) * BD + col] = a3 + bb;
}

__global__ __launch_bounds__(256) void proj_kernel(
    const float* __restrict__ x,
    const float* __restrict__ Wk, const float* __restrict__ bk,
    const float* __restrict__ Wv, const float* __restrict__ bv,
    const float* __restrict__ Wq, const float* __restrict__ bq,
    float* __restrict__ Kout, float* __restrict__ Vout,
    float* __restrict__ Qout) {
  __shared__ __align__(16) float xs[16 * D];  // 32 KB
  const int tid = threadIdx.x;
  const size_t row0 = (size_t)blockIdx.x * 16;
  const float4* xg = (const float4*)(x + row0 * D);
  float4* xs4 = (float4*)xs;
#pragma unroll
  for (int i = 0; i < 8; i++) xs4[i * 256 + tid] = xg[i * 256 + tid];
  __syncthreads();
  const int col = tid & 63;
  const int rg = tid >> 6;  // 4 row-groups of 4 rows
  do_proj(Wk, bk, Kout, xs, col, rg, row0);
  do_proj(Wv, bv, Vout, xs, col, rg, row0);
  do_proj(Wq, bq, Qout, xs, col, rg, row0);
}

// ---------------- eta = sigmoid(x . lr_w + lr_b) ----------------
__global__ __launch_bounds__(256) void eta_kernel(const float* __restrict__ x,
                                                  const float* __restrict__ lr_w,
                                                  const float* __restrict__ lr_b,
                                                  float* __restrict__ eta) {
  const int tid = threadIdx.x;
  const int lane = tid & 63;
  const int wv = tid >> 6;
  const size_t r = (size_t)blockIdx.x * 4 + wv;  // one wave per row
  const float* xr = x + r * D + lane * 8;
  float4 a = *(const float4*)xr;
  float4 b = *(const float4*)(xr + 4);
  const float* lw = lr_w + lane * 8;
  float4 la = *(const float4*)lw;
  float4 lb = *(const float4*)(lw + 4);
  float p = a.x * la.x + a.y * la.y + a.z * la.z + a.w * la.w +
            b.x * lb.x + b.y * lb.y + b.z * lb.z + b.w * lb.w;
#pragma unroll
  for (int m = 32; m > 0; m >>= 1) p += __shfl_xor(p, m, 64);
  if (lane == 0) eta[r] = 1.0f / (1.0f + expf(-(p + lr_b[0])));
}

// ---------------- sequential TTT scan: FOUR waves per batch element --------
// Round 6 restructure (resubmit after container-infra failure; eta prefetch
// now clamped so no read depends on ws slack).
// Rationale: one wave per CU is capped at ~1 instr per 4-cycle SIMD visit
// (measured 2638 cyc/step vs ~660 theoretical 2cy-issue). Split the per-step
// work across 4 waves on 4 SIMDs of one CU:
//  * wave w owns W columns [16w,16w+16) -> matvecs & W-update are 48 FMAs/wave
//    instead of 192.
//  * u/p partials combined through 4KB LDS, double-buffered by step parity,
//    ONE __syncthreads per step (write_t(p) < bar_t < read_t(p) < bar_{t+1}
//    < write_{t+2}(p) -- race-free).
//  * k/q broadcast slices for step t+1 are loaded with WAVE-UNIFORM addresses
//    straight from global (-> s_load, scalar pipe, SGPR operands) instead of
//    the old 32x ds_read_b128 LDS round-trip. sched_barrier(0) fences keep
//    them from mixing with the combine ds_reads' lgkmcnt waits.
//  * Sc / Qk reductions hoisted pre-barrier; Qk, u2, phase-2 LN and the H
//    store run on wave 0 only.
//  * LN-grad allsums + scalar chain stay replicated per wave (serial math).
__global__ __launch_bounds__(256, 1)
void ttt_seq_kernel(
    const float* __restrict__ Kin, const float* __restrict__ Vin,
    const float* __restrict__ Qin, const float* __restrict__ eta_in,
    const float* __restrict__ W0, const float* __restrict__ ln_g,
    const float* __restrict__ ln_b, float* __restrict__ Hout) {
  __shared__ __align__(16) float2 part[2][4][64];  // 4 KB, parity-double-buffered
  const int tid = threadIdx.x;
  const int lane = tid & 63;
  // uniform wave id (readfirstlane -> SGPR; threadIdx>>6 alone is not provably
  // uniform, which would demote the slice loads to vector loads)
  const int wvu = __builtin_amdgcn_readfirstlane(tid) >> 6;
  const int b = blockIdx.x;

  // W slice: w[j] = W0[lane*BD + 16*wvu + j], j = 0..15
  float w[16];
  {
    const float4* w04 = (const float4*)(W0 + (size_t)lane * BD + wvu * 16);
#pragma unroll
    for (int i = 0; i < 4; i++) {
      float4 t4 = w04[i];
      w[4 * i] = t4.x; w[4 * i + 1] = t4.y; w[4 * i + 2] = t4.z; w[4 * i + 3] = t4.w;
    }
  }
  const float g = ln_g[lane];
  const float bet = ln_b[lane];
  const float a = g * g;
  const float A2 = wave_allsum(a);

  size_t base = (size_t)b * T * BD;
  size_t ebase = (size_t)b * T;

  // per-lane global ring, distance 4 (replicated in all 4 waves; same
  // addresses -> L1 broadcast)
  float pk[4], pv[4], pq[4];
#pragma unroll
  for (int j = 0; j < 4; j++) {
    pk[j] = Kin[base + j * BD + lane];
    pv[j] = Vin[base + j * BD + lane];
    pq[j] = Qin[base + j * BD + lane];
  }
  // eta chunks (64 steps per chunk)
  float ev  = eta_in[ebase + lane];        // chunk 0
  float evn = eta_in[ebase + 64 + lane];   // chunk 1

  // k_0 / q_0 slices for this wave (uniform address -> s_load)
  float4 kc[4], qc[4];
  {
    const float* kr = Kin + base + (size_t)(wvu * 16);
    const float* qr = Qin + base + (size_t)(wvu * 16);
#pragma unroll
    for (int i = 0; i < 4; i++) {
      kc[i] = ((const float4*)kr)[i];
      qc[i] = ((const float4*)qr)[i];
    }
  }

  for (int c = 0; c < 32; c++) {
    // issue chunk c+2's eta load now (64 bodies of cover); clamp final chunk
    // so the prefetch never leaves the ETA region.
    size_t eoff = (size_t)(c + 2) * 64;
    if (eoff >= T) eoff = 0;
    float ev2 = eta_in[ebase + eoff + lane];

    for (int g4 = 0; g4 < 16; g4++) {
#pragma unroll
      for (int j = 0; j < 4; j++) {
        const int p = j & 1;  // partial-buffer parity
        const int i_in_chunk = (g4 << 2) + j;

        float kcur = pk[j], vcur = pv[j], qcur = pq[j];
        float ecur = __int_as_float(
            __builtin_amdgcn_readlane(__float_as_int(ev), i_in_chunk));

        // reload stage j for t+4 (off-end reads stay inside d_ws)
        pk[j] = Kin[base + 4 * BD + lane];
        pv[j] = Vin[base + 4 * BD + lane];
        pq[j] = Qin[base + 4 * BD + lane];

        // partial matvecs over this wave's 16-column slice
        float u0 = 0.f, u1 = 0.f, u2s = 0.f, u3 = 0.f;
        float p0 = 0.f, p1 = 0.f, p2s = 0.f, p3 = 0.f;
#pragma unroll
        for (int i = 0; i < 4; i++) {
          u0  += kc[i].x * w[4 * i + 0];
          u1  += kc[i].y * w[4 * i + 1];
          u2s += kc[i].z * w[4 * i + 2];
          u3  += kc[i].w * w[4 * i + 3];
          p0  += qc[i].x * w[4 * i + 0];
          p1  += qc[i].y * w[4 * i + 1];
          p2s += qc[i].z * w[4 * i + 2];
          p3  += qc[i].w * w[4 * i + 3];
        }
        part[p][wvu][lane] = make_float2((u0 + u1) + (u2s + u3),
                                         (p0 + p1) + (p2s + p3));

        // pre-barrier independent reductions (no u dependence)
        float c0 = g * (kcur + bet - vcur);
        float Sc = wave_allsum(c0);
        float Qk = 0.f;
        if (wvu == 0) Qk = wave_allsum(qcur * kcur);  // only wave 0 needs q.k

        __syncthreads();

        // combine partials -> full u, p
        float2 pA = part[p][0][lane];
        float2 pB = part[p][1][lane];
        float2 pC = part[p][2][lane];
        float2 pD = part[p][3][lane];
        float u     = (pA.x + pB.x) + (pC.x + pD.x);
        float pfull = (pA.y + pB.y) + (pC.y + pD.y);
        __builtin_amdgcn_sched_barrier(0);
        // slice loads for t+1 (uniform -> s_load). Fenced so they issue AFTER
        // the combine ds_reads' lgkmcnt wait (avoids the mixed SMEM/DS
        // lgkmcnt(0) drain), and before the allsum/scalar phase (~300 cy of
        // latency cover to their first use next body).
        float4 kn[4], qn[4];
        {
          const float* kr = Kin + base + BD + (size_t)(wvu * 16);
          const float* qr = Qin + base + BD + (size_t)(wvu * 16);
#pragma unroll
          for (int i = 0; i < 4; i++) {
            kn[i] = ((const float4*)kr)[i];
            qn[i] = ((const float4*)qr)[i];
          }
        }
        __builtin_amdgcn_sched_barrier(0);

        // u-dependent reductions (replicated per wave)
        float Su   = wave_allsum(u);
        float Suu  = wave_allsum(u * u);
        float Sau  = wave_allsum(a * u);
        float Sauu = wave_allsum(a * u * u);
        float Scu  = wave_allsum(c0 * u);

        float mu = Su * (1.0f / 64);
        float var = Suu * (1.0f / 64) - mu * mu;
        float rstd = rsqrtf(var + 1e-6f);
        float xh = (u - mu) * rstd;
        float Axh   = rstd * (Sau - mu * A2);
        float Scxh  = rstd * (Scu - mu * Sc);
        float Saxh2 = rstd * rstd * (Sauu - 2.0f * mu * Sau + mu * mu * A2);
        float s1 = (2.0f / 64) * (Sc + Axh);
        float s2 = (2.0f / 64) * (Scxh + Saxh2);
        float dxh = (2.0f / 64) * (c0 + a * xh);
        float dldu = rstd * (dxh - s1 * (1.0f / 64) - xh * (s2 * (1.0f / 64)));
        float coef = -ecur * dldu;  // W_new row o = w + coef*k

        // W-slice update (last use of kc this step)
#pragma unroll
        for (int i = 0; i < 4; i++) {
          w[4 * i + 0] += coef * kc[i].x;
          w[4 * i + 1] += coef * kc[i].y;
          w[4 * i + 2] += coef * kc[i].z;
          w[4 * i + 3] += coef * kc[i].w;
        }

        // phase 2: LN of u2 + output -- wave 0 only
        if (wvu == 0) {
          float u2 = pfull + coef * Qk;  // q @ W_new^T
          float Su2  = wave_allsum(u2);
          float Suu2 = wave_allsum(u2 * u2);
          float mu2 = Su2 * (1.0f / 64);
          float rstd2 = rsqrtf(Suu2 * (1.0f / 64) - mu2 * mu2 + 1e-6f);
          Hout[base + lane] = qcur + (u2 - mu2) * rstd2 * g + bet;
        }

        // advance slice regs (SSA-renamed by the unroll; the lgkmcnt wait for
        // kn/qn lands at their first real use next body)
#pragma unroll
        for (int i = 0; i < 4; i++) { kc[i] = kn[i]; qc[i] = qn[i]; }
        base += BD;
      }
    }
    ev = evn; evn = ev2;
  }
}

// ---------------- out projection: z = H @ Wo + bo ----------------
__global__ __launch_bounds__(256) void outproj_kernel(
    const float* __restrict__ H, const float* __restrict__ Wo,
    const float* __restrict__ bo, float* __restrict__ out) {
  __shared__ __align__(16) float ht[16 * BD];  // 4 KB
  const int tid = threadIdx.x;
  const size_t row0 = (size_t)blockIdx.x * 16;
  ((float4*)ht)[tid] = ((const float4*)(H + row0 * BD))[tid];
  __syncthreads();
  float acc0[16], acc1[16];
#pragma unroll
  for (int r = 0; r < 16; r++) { acc0[r] = 0.f; acc1[r] = 0.f; }
  for (int kk = 0; kk < BD; kk++) {
    float w0 = Wo[kk * D + tid];
    float w1 = Wo[kk * D + tid + 256];
#pragma unroll
    for (int r = 0; r < 16; r++) {
      float hv = ht[r * BD + kk];
      acc0[r] += hv * w0;
      acc1[r] += hv * w1;
    }
  }
  float b0 = bo[tid], b1 = bo[tid + 256];
#pragma unroll
  for (int r = 0; r < 16; r++) {
    out[(row0 + r) * D + tid] = acc0[r] + b0;
    out[(row0 + r) * D + tid + 256] = acc1[r] + b1;
  }
}

extern "C" void kernel_launch(void* const* d_in, const int* in_sizes, int n_in,
                              void* d_out, int out_size, void* d_ws,
                              size_t ws_size, hipStream_t stream) {
  (void)in_sizes; (void)n_in; (void)out_size; (void)ws_size;
  const float* x    = (const float*)d_in[0];
  const float* Wk   = (const float*)d_in[1];
  const float* bk   = (const float*)d_in[2];
  const float* Wv   = (const float*)d_in[3];
  const float* bv   = (const float*)d_in[4];
  const float* Wq   = (const float*)d_in[5];
  const float* bq   = (const float*)d_in[6];
  const float* Wo   = (const float*)d_in[7];
  const float* bo   = (const float*)d_in[8];
  const float* ln_g = (const float*)d_in[9];
  const float* ln_b = (const float*)d_in[10];
  const float* lr_w = (const float*)d_in[11];
  const float* lr_b = (const float*)d_in[12];
  const float* W0   = (const float*)d_in[13];

  float* ws  = (float*)d_ws;
  float* Kb  = ws + OFF_K;
  float* Vb  = ws + OFF_V;
  float* Qb  = ws + OFF_Q;
  float* ETA = ws + OFF_ETA;
  float* Hb  = ws + OFF_H;
  float* out = (float*)d_out;

  proj_kernel<<<BT / 16, 256, 0, stream>>>(x, Wk, bk, Wv, bv, Wq, bq, Kb, Vb, Qb);
  eta_kernel<<<BT / 4, 256, 0, stream>>>(x, lr_w, lr_b, ETA);
  ttt_seq_kernel<<<NB, 256, 0, stream>>>(Kb, Vb, Qb, ETA, W0, ln_g, ln_b, Hb);
  outproj_kernel<<<BT / 16, 256, 0, stream>>>(Hb, Wo, bo, out);
}

// Round 3
// 1724.633 us; speedup vs baseline: 1.4924x; 1.0775x over previous
//
#include <hip/hip_runtime.h>
#include <math.h>

#define NB 16
#define T  2048
#define D  512
#define BD 64
#define BT (NB*T)  // 32768

// workspace layout (float offsets)
#define OFF_K   0
#define OFF_V   (BT*BD)
#define OFF_Q   (2*BT*BD)
#define OFF_ETA (3*BT*BD)
#define OFF_H   (3*BT*BD + BT)
// total floats = 4*BT*BD + BT = 8,421,376  (~33.7 MB)

// ---------------- DPP full-wave sum, result broadcast to all lanes ----------
__device__ __forceinline__ float wave_allsum(float x) {
  x += __int_as_float(__builtin_amdgcn_update_dpp(
      0, __float_as_int(x), 0x111, 0xf, 0xf, true));   // row_shr:1
  x += __int_as_float(__builtin_amdgcn_update_dpp(
      0, __float_as_int(x), 0x112, 0xf, 0xf, true));   // row_shr:2
  x += __int_as_float(__builtin_amdgcn_update_dpp(
      0, __float_as_int(x), 0x114, 0xf, 0xf, true));   // row_shr:4
  x += __int_as_float(__builtin_amdgcn_update_dpp(
      0, __float_as_int(x), 0x118, 0xf, 0xf, true));   // row_shr:8
  x += __int_as_float(__builtin_amdgcn_update_dpp(
      0, __float_as_int(x), 0x142, 0xa, 0xf, false));  // row_bcast:15 -> rows 1,3
  x += __int_as_float(__builtin_amdgcn_update_dpp(
      0, __float_as_int(x), 0x143, 0xc, 0xf, false));  // row_bcast:31 -> rows 2,3
  return __int_as_float(__builtin_amdgcn_readlane(__float_as_int(x), 63));
}

// Raw workgroup barrier that waits ONLY on DS ops (lgkmcnt(0)), leaving
// global loads (vmcnt) in flight across it. __syncthreads() would emit
// s_waitcnt vmcnt(0) lgkmcnt(0) and kill every prefetch pipeline each step.
// Safe here because the loop body contains NO SMEM loads (lgkm = DS only).
__device__ __forceinline__ void lds_barrier() {
  __builtin_amdgcn_sched_barrier(0);
  __builtin_amdgcn_s_waitcnt(0xC07F);  // vmcnt=63 (no wait), expcnt=7, lgkmcnt=0
  __builtin_amdgcn_s_barrier();
  __builtin_amdgcn_sched_barrier(0);
}

// ---------------- projection: K,V,Q = x @ W{k,v,q} + b ----------------
__device__ __forceinline__ void do_proj(const float* __restrict__ W,
                                        const float* __restrict__ bias,
                                        float* __restrict__ Out,
                                        const float* xs, int col, int rg,
                                        size_t row0) {
  float a0 = 0.f, a1 = 0.f, a2 = 0.f, a3 = 0.f;
  for (int d = 0; d < D; d += 4) {
    float w0 = W[(d + 0) * BD + col];
    float w1 = W[(d + 1) * BD + col];
    float w2 = W[(d + 2) * BD + col];
    float w3 = W[(d + 3) * BD + col];
    const float* xb = xs + (rg * 4) * D + d;
    float4 x0 = *(const float4*)(xb);
    float4 x1 = *(const float4*)(xb + D);
    float4 x2 = *(const float4*)(xb + 2 * D);
    float4 x3 = *(const float4*)(xb + 3 * D);
    a0 += x0.x * w0 + x0.y * w1 + x0.z * w2 + x0.w * w3;
    a1 += x1.x * w0 + x1.y * w1 + x1.z * w2 + x1.w * w3;
    a2 += x2.x * w0 + x2.y * w1 + x2.z * w2 + x2.w * w3;
    a3 += x3.x * w0 + x3.y * w1 + x3.z * w2 + x3.w * w3;
  }
  float bb = bias[col];
  Out[(row0 + rg * 4 + 0) * BD + col] = a0 + bb;
  Out[(row0 + rg * 4 + 1) * BD + col] = a1 + bb;
  Out[(row0 + rg * 4 + 2) * BD + col] = a2 + bb;
  Out[(row0 + rg * 4 + 3) * BD + col] = a3 + bb;
}

__global__ __launch_bounds__(256) void proj_kernel(
    const float* __restrict__ x,
    const float* __restrict__ Wk, const float* __restrict__ bk,
    const float* __restrict__ Wv, const float* __restrict__ bv,
    const float* __restrict__ Wq, const float* __restrict__ bq,
    float* __restrict__ Kout, float* __restrict__ Vout,
    float* __restrict__ Qout) {
  __shared__ __align__(16) float xs[16 * D];  // 32 KB
  const int tid = threadIdx.x;
  const size_t row0 = (size_t)blockIdx.x * 16;
  const float4* xg = (const float4*)(x + row0 * D);
  float4* xs4 = (float4*)xs;
#pragma unroll
  for (int i = 0; i < 8; i++) xs4[i * 256 + tid] = xg[i * 256 + tid];
  __syncthreads();
  const int col = tid & 63;
  const int rg = tid >> 6;  // 4 row-groups of 4 rows
  do_proj(Wk, bk, Kout, xs, col, rg, row0);
  do_proj(Wv, bv, Vout, xs, col, rg, row0);
  do_proj(Wq, bq, Qout, xs, col, rg, row0);
}

// ---------------- eta = sigmoid(x . lr_w + lr_b) ----------------
__global__ __launch_bounds__(256) void eta_kernel(const float* __restrict__ x,
                                                  const float* __restrict__ lr_w,
                                                  const float* __restrict__ lr_b,
                                                  float* __restrict__ eta) {
  const int tid = threadIdx.x;
  const int lane = tid & 63;
  const int wv = tid >> 6;
  const size_t r = (size_t)blockIdx.x * 4 + wv;  // one wave per row
  const float* xr = x + r * D + lane * 8;
  float4 a = *(const float4*)xr;
  float4 b = *(const float4*)(xr + 4);
  const float* lw = lr_w + lane * 8;
  float4 la = *(const float4*)lw;
  float4 lb = *(const float4*)(lw + 4);
  float p = a.x * la.x + a.y * la.y + a.z * la.z + a.w * la.w +
            b.x * lb.x + b.y * lb.y + b.z * lb.z + b.w * lb.w;
#pragma unroll
  for (int m = 32; m > 0; m >>= 1) p += __shfl_xor(p, m, 64);
  if (lane == 0) eta[r] = 1.0f / (1.0f + expf(-(p + lr_b[0])));
}

// ---------------- sequential TTT scan: FOUR waves per batch element --------
// Round 7: keep the 4-wave split (r6: 2250->1527us) but remove the two
// structural stalls r6's counters exposed (1790 cyc/step vs ~600 modeled):
//  1. __syncthreads -> raw s_barrier + lgkmcnt(0)-only wait. __syncthreads
//     drains vmcnt(0) every step, nullifying the distance-4 global ring
//     prefetch (L2 latency ~200-300cy paid at every barrier).
//  2. slice loads were s_load (SMEM); SMEM+DS share lgkmcnt and complete
//     out-of-order, so the combine's wait became lgkmcnt(0) and drained
//     just-issued scalar-cache misses on the critical path. Now forced to
//     VECTOR global loads (opaque VGPR zero in the address), vmcnt-tracked,
//     parity-double-buffered in registers, issued BEFORE the barrier so
//     latency overlaps barrier+combine; consumed next body.
//  3. phase-2 (output LN + H store) is a pure sink -> deferred & distributed:
//     wave j saves {u2, q} for step 4s+j (it alone does the Qk allsum that
//     step); every 4 steps all waves finalize their own step in parallel.
__global__ __launch_bounds__(256, 1)
void ttt_seq_kernel(
    const float* __restrict__ Kin, const float* __restrict__ Vin,
    const float* __restrict__ Qin, const float* __restrict__ eta_in,
    const float* __restrict__ W0, const float* __restrict__ ln_g,
    const float* __restrict__ ln_b, float* __restrict__ Hout) {
  __shared__ __align__(16) float2 part[2][4][64];  // 4 KB, parity-double-buffered
  const int tid = threadIdx.x;
  const int lane = tid & 63;
  const int wvu = __builtin_amdgcn_readfirstlane(tid) >> 6;
  const int b = blockIdx.x;

  // opaque zero in a VGPR: forces slice-load addresses to be divergent so the
  // compiler emits global_load (vmcnt) instead of s_load (lgkmcnt).
  int vzero;
  asm("v_mov_b32 %0, 0" : "=v"(vzero));

  // W slice: w[j] = W0[lane*BD + 16*wvu + j], j = 0..15
  float w[16];
  {
    const float4* w04 = (const float4*)(W0 + (size_t)lane * BD + wvu * 16);
#pragma unroll
    for (int i = 0; i < 4; i++) {
      float4 t4 = w04[i];
      w[4 * i] = t4.x; w[4 * i + 1] = t4.y; w[4 * i + 2] = t4.z; w[4 * i + 3] = t4.w;
    }
  }
  const float g = ln_g[lane];
  const float bet = ln_b[lane];
  const float a = g * g;
  const float A2 = wave_allsum(a);

  size_t base = (size_t)b * T * BD;
  size_t ebase = (size_t)b * T;

  // per-lane global ring, distance 4 (replicated across waves; L1-broadcast)
  float pk[4], pv[4], pq[4];
#pragma unroll
  for (int j = 0; j < 4; j++) {
    pk[j] = Kin[base + j * BD + lane];
    pv[j] = Vin[base + j * BD + lane];
    pq[j] = Qin[base + j * BD + lane];
  }
  // eta chunks (64 steps per chunk)
  float ev  = eta_in[ebase + lane];        // chunk 0
  float evn = eta_in[ebase + 64 + lane];   // chunk 1

  // slice double-buffer (registers; static indices after unroll)
  float4 kcA[4], qcA[4], kcB[4], qcB[4];
  {
    const float* kr = Kin + base + (size_t)(wvu * 16) + vzero;
    const float* qr = Qin + base + (size_t)(wvu * 16) + vzero;
#pragma unroll
    for (int i = 0; i < 4; i++) {
      kcA[i] = ((const float4*)kr)[i];
      qcA[i] = ((const float4*)qr)[i];
    }
  }
  float u2s_ = 0.f, qs_ = 0.f;  // deferred phase-2 state (one step per wave)

  for (int c = 0; c < 32; c++) {
    // chunk c+2's eta load (64 bodies of cover); clamped in-region
    size_t eoff = (size_t)(c + 2) * 64;
    if (eoff >= T) eoff = 0;
    float ev2 = eta_in[ebase + eoff + lane];

    for (int g4 = 0; g4 < 16; g4++) {
#pragma unroll
      for (int j = 0; j < 4; j++) {
        const int pt = j & 1;  // LDS-partial & slice-buffer parity
        const float4* ku = pt ? kcB : kcA;
        const float4* qu = pt ? qcB : qcA;
        float4* kn = pt ? kcA : kcB;
        float4* qn = pt ? qcA : qcB;
        const int i_in_chunk = (g4 << 2) + j;

        float kcur = pk[j], vcur = pv[j], qcur = pq[j];
        float ecur = __int_as_float(
            __builtin_amdgcn_readlane(__float_as_int(ev), i_in_chunk));

        // ring reload for t+4 (stays in flight across the raw barrier now)
        pk[j] = Kin[base + 4 * BD + lane];
        pv[j] = Vin[base + 4 * BD + lane];
        pq[j] = Qin[base + 4 * BD + lane];

        // partial matvecs over this wave's 16-column slice
        float u0 = 0.f, u1 = 0.f, u2p = 0.f, u3 = 0.f;
        float p0 = 0.f, p1 = 0.f, p2p = 0.f, p3 = 0.f;
#pragma unroll
        for (int i = 0; i < 4; i++) {
          u0  += ku[i].x * w[4 * i + 0];
          u1  += ku[i].y * w[4 * i + 1];
          u2p += ku[i].z * w[4 * i + 2];
          u3  += ku[i].w * w[4 * i + 3];
          p0  += qu[i].x * w[4 * i + 0];
          p1  += qu[i].y * w[4 * i + 1];
          p2p += qu[i].z * w[4 * i + 2];
          p3  += qu[i].w * w[4 * i + 3];
        }
        part[pt][wvu][lane] = make_float2((u0 + u1) + (u2p + u3),
                                          (p0 + p1) + (p2p + p3));

        // pre-barrier reductions (independent of u)
        float c0 = g * (kcur + bet - vcur);
        float Sc = wave_allsum(c0);
        float Qk = 0.f;
        if (wvu == j) Qk = wave_allsum(qcur * kcur);  // owner of step t only

        // slice prefetch for t+1: vector loads, issued BEFORE the barrier so
        // ~a full body of latency cover; consumed at next body's FMAs.
        {
          const float* kr = Kin + base + BD + (size_t)(wvu * 16) + vzero;
          const float* qr = Qin + base + BD + (size_t)(wvu * 16) + vzero;
#pragma unroll
          for (int i = 0; i < 4; i++) {
            kn[i] = ((const float4*)kr)[i];
            qn[i] = ((const float4*)qr)[i];
          }
        }

        lds_barrier();  // lgkmcnt(0)-only wait + raw s_barrier

        // combine partials -> full u, p
        float2 pA = part[pt][0][lane];
        float2 pB = part[pt][1][lane];
        float2 pC = part[pt][2][lane];
        float2 pD = part[pt][3][lane];
        float u     = (pA.x + pB.x) + (pC.x + pD.x);
        float pfull = (pA.y + pB.y) + (pC.y + pD.y);

        // u-dependent reductions (replicated per wave)
        float Su   = wave_allsum(u);
        float Suu  = wave_allsum(u * u);
        float Sau  = wave_allsum(a * u);
        float Sauu = wave_allsum(a * u * u);
        float Scu  = wave_allsum(c0 * u);

        float mu = Su * (1.0f / 64);
        float var = Suu * (1.0f / 64) - mu * mu;
        float rstd = rsqrtf(var + 1e-6f);
        float xh = (u - mu) * rstd;
        float Axh   = rstd * (Sau - mu * A2);
        float Scxh  = rstd * (Scu - mu * Sc);
        float Saxh2 = rstd * rstd * (Sauu - 2.0f * mu * Sau + mu * mu * A2);
        float s1 = (2.0f / 64) * (Sc + Axh);
        float s2 = (2.0f / 64) * (Scxh + Saxh2);
        float dxh = (2.0f / 64) * (c0 + a * xh);
        float dldu = rstd * (dxh - s1 * (1.0f / 64) - xh * (s2 * (1.0f / 64)));
        float coef = -ecur * dldu;  // W_new row o = w + coef*k

        // save deferred phase-2 state for the step this wave owns
        if (wvu == j) { u2s_ = pfull + coef * Qk; qs_ = qcur; }

        // W-slice update (last use of ku this step)
#pragma unroll
        for (int i = 0; i < 4; i++) {
          w[4 * i + 0] += coef * ku[i].x;
          w[4 * i + 1] += coef * ku[i].y;
          w[4 * i + 2] += coef * ku[i].z;
          w[4 * i + 3] += coef * ku[i].w;
        }

        base += BD;
      }

      // deferred phase-2 flush: each wave finalizes its own step (group+wvu),
      // all four in parallel, off the inter-step critical path. No barrier
      // needed (intra-wave only).
      {
        float u2 = u2s_;
        float Su2  = wave_allsum(u2);
        float Suu2 = wave_allsum(u2 * u2);
        float mu2 = Su2 * (1.0f / 64);
        float rstd2 = rsqrtf(Suu2 * (1.0f / 64) - mu2 * mu2 + 1e-6f);
        size_t hb = base - (size_t)(4 - wvu) * BD;
        Hout[hb + lane] = qs_ + (u2 - mu2) * rstd2 * g + bet;
      }
    }
    ev = evn; evn = ev2;
  }
}

// ---------------- out projection: z = H @ Wo + bo ----------------
__global__ __launch_bounds__(256) void outproj_kernel(
    const float* __restrict__ H, const float* __restrict__ Wo,
    const float* __restrict__ bo, float* __restrict__ out) {
  __shared__ __align__(16) float ht[16 * BD];  // 4 KB
  const int tid = threadIdx.x;
  const size_t row0 = (size_t)blockIdx.x * 16;
  ((float4*)ht)[tid] = ((const float4*)(H + row0 * BD))[tid];
  __syncthreads();
  float acc0[16], acc1[16];
#pragma unroll
  for (int r = 0; r < 16; r++) { acc0[r] = 0.f; acc1[r] = 0.f; }
  for (int kk = 0; kk < BD; kk++) {
    float w0 = Wo[kk * D + tid];
    float w1 = Wo[kk * D + tid + 256];
#pragma unroll
    for (int r = 0; r < 16; r++) {
      float hv = ht[r * BD + kk];
      acc0[r] += hv * w0;
      acc1[r] += hv * w1;
    }
  }
  float b0 = bo[tid], b1 = bo[tid + 256];
#pragma unroll
  for (int r = 0; r < 16; r++) {
    out[(row0 + r) * D + tid] = acc0[r] + b0;
    out[(row0 + r) * D + tid + 256] = acc1[r] + b1;
  }
}

extern "C" void kernel_launch(void* const* d_in, const int* in_sizes, int n_in,
                              void* d_out, int out_size, void* d_ws,
                              size_t ws_size, hipStream_t stream) {
  (void)in_sizes; (void)n_in; (void)out_size; (void)ws_size;
  const float* x    = (const float*)d_in[0];
  const float* Wk   = (const float*)d_in[1];
  const float* bk   = (const float*)d_in[2];
  const float* Wv   = (const float*)d_in[3];
  const float* bv   = (const float*)d_in[4];
  const float* Wq   = (const float*)d_in[5];
  const float* bq   = (const float*)d_in[6];
  const float* Wo   = (const float*)d_in[7];
  const float* bo   = (const float*)d_in[8];
  const float* ln_g = (const float*)d_in[9];
  const float* ln_b = (const float*)d_in[10];
  const float* lr_w = (const float*)d_in[11];
  const float* lr_b = (const float*)d_in[12];
  const float* W0   = (const float*)d_in[13];

  float* ws  = (float*)d_ws;
  float* Kb  = ws + OFF_K;
  float* Vb  = ws + OFF_V;
  float* Qb  = ws + OFF_Q;
  float* ETA = ws + OFF_ETA;
  float* Hb  = ws + OFF_H;
  float* out = (float*)d_out;

  proj_kernel<<<BT / 16, 256, 0, stream>>>(x, Wk, bk, Wv, bv, Wq, bq, Kb, Vb, Qb);
  eta_kernel<<<BT / 4, 256, 0, stream>>>(x, lr_w, lr_b, ETA);
  ttt_seq_kernel<<<NB, 256, 0, stream>>>(Kb, Vb, Qb, ETA, W0, ln_g, ln_b, Hb);
  outproj_kernel<<<BT / 16, 256, 0, stream>>>(Hb, Wo, bo, out);
}

// Round 4
// 1436.473 us; speedup vs baseline: 1.7918x; 1.2006x over previous
//
#include <hip/hip_runtime.h>
#include <math.h>

#define NB 16
#define T  2048
#define D  512
#define BD 64
#define BT (NB*T)  // 32768

// workspace layout (float offsets)
#define OFF_K   0
#define OFF_V   (BT*BD)
#define OFF_Q   (2*BT*BD)
#define OFF_ETA (3*BT*BD)
#define OFF_H   (3*BT*BD + BT)
// total floats = 4*BT*BD + BT = 8,421,376  (~33.7 MB)

// gram scratch lives in d_out (64 MB; overwritten later by outproj):
// per 16-step chunk: KK[16*16] | KQ[16*16] | SC[16] | pad -> 544 floats
#define GSTRIDE 544
#define NCHUNK  (BT/16)   // 2048

// ---------------- DPP full-wave sum, result broadcast to all lanes ----------
__device__ __forceinline__ float wave_allsum(float x) {
  x += __int_as_float(__builtin_amdgcn_update_dpp(
      0, __float_as_int(x), 0x111, 0xf, 0xf, true));   // row_shr:1
  x += __int_as_float(__builtin_amdgcn_update_dpp(
      0, __float_as_int(x), 0x112, 0xf, 0xf, true));   // row_shr:2
  x += __int_as_float(__builtin_amdgcn_update_dpp(
      0, __float_as_int(x), 0x114, 0xf, 0xf, true));   // row_shr:4
  x += __int_as_float(__builtin_amdgcn_update_dpp(
      0, __float_as_int(x), 0x118, 0xf, 0xf, true));   // row_shr:8
  x += __int_as_float(__builtin_amdgcn_update_dpp(
      0, __float_as_int(x), 0x142, 0xa, 0xf, false));  // row_bcast:15 -> rows 1,3
  x += __int_as_float(__builtin_amdgcn_update_dpp(
      0, __float_as_int(x), 0x143, 0xc, 0xf, false));  // row_bcast:31 -> rows 2,3
  return __int_as_float(__builtin_amdgcn_readlane(__float_as_int(x), 63));
}

// DS-only barrier: waits lgkmcnt(0) (all loop lgkm ops are DS), leaves vmcnt
// in flight. Proven in r3.
__device__ __forceinline__ void lds_barrier() {
  __builtin_amdgcn_sched_barrier(0);
  __builtin_amdgcn_s_waitcnt(0xC07F);  // vmcnt=63 (no wait), expcnt=7, lgkmcnt=0
  __builtin_amdgcn_s_barrier();
  __builtin_amdgcn_sched_barrier(0);
}

// ---------------- projection: K,V,Q = x @ W{k,v,q} + b ----------------
__device__ __forceinline__ void do_proj(const float* __restrict__ W,
                                        const float* __restrict__ bias,
                                        float* __restrict__ Out,
                                        const float* xs, int col, int rg,
                                        size_t row0) {
  float a0 = 0.f, a1 = 0.f, a2 = 0.f, a3 = 0.f;
  for (int d = 0; d < D; d += 4) {
    float w0 = W[(d + 0) * BD + col];
    float w1 = W[(d + 1) * BD + col];
    float w2 = W[(d + 2) * BD + col];
    float w3 = W[(d + 3) * BD + col];
    const float* xb = xs + (rg * 4) * D + d;
    float4 x0 = *(const float4*)(xb);
    float4 x1 = *(const float4*)(xb + D);
    float4 x2 = *(const float4*)(xb + 2 * D);
    float4 x3 = *(const float4*)(xb + 3 * D);
    a0 += x0.x * w0 + x0.y * w1 + x0.z * w2 + x0.w * w3;
    a1 += x1.x * w0 + x1.y * w1 + x1.z * w2 + x1.w * w3;
    a2 += x2.x * w0 + x2.y * w1 + x2.z * w2 + x2.w * w3;
    a3 += x3.x * w0 + x3.y * w1 + x3.z * w2 + x3.w * w3;
  }
  float bb = bias[col];
  Out[(row0 + rg * 4 + 0) * BD + col] = a0 + bb;
  Out[(row0 + rg * 4 + 1) * BD + col] = a1 + bb;
  Out[(row0 + rg * 4 + 2) * BD + col] = a2 + bb;
  Out[(row0 + rg * 4 + 3) * BD + col] = a3 + bb;
}

__global__ __launch_bounds__(256) void proj_kernel(
    const float* __restrict__ x,
    const float* __restrict__ Wk, const float* __restrict__ bk,
    const float* __restrict__ Wv, const float* __restrict__ bv,
    const float* __restrict__ Wq, const float* __restrict__ bq,
    float* __restrict__ Kout, float* __restrict__ Vout,
    float* __restrict__ Qout) {
  __shared__ __align__(16) float xs[16 * D];  // 32 KB
  const int tid = threadIdx.x;
  const size_t row0 = (size_t)blockIdx.x * 16;
  const float4* xg = (const float4*)(x + row0 * D);
  float4* xs4 = (float4*)xs;
#pragma unroll
  for (int i = 0; i < 8; i++) xs4[i * 256 + tid] = xg[i * 256 + tid];
  __syncthreads();
  const int col = tid & 63;
  const int rg = tid >> 6;  // 4 row-groups of 4 rows
  do_proj(Wk, bk, Kout, xs, col, rg, row0);
  do_proj(Wv, bv, Vout, xs, col, rg, row0);
  do_proj(Wq, bq, Qout, xs, col, rg, row0);
}

// ---------------- eta = sigmoid(x . lr_w + lr_b) ----------------
__global__ __launch_bounds__(256) void eta_kernel(const float* __restrict__ x,
                                                  const float* __restrict__ lr_w,
                                                  const float* __restrict__ lr_b,
                                                  float* __restrict__ eta) {
  const int tid = threadIdx.x;
  const int lane = tid & 63;
  const int wv = tid >> 6;
  const size_t r = (size_t)blockIdx.x * 4 + wv;  // one wave per row
  const float* xr = x + r * D + lane * 8;
  float4 a = *(const float4*)xr;
  float4 b = *(const float4*)(xr + 4);
  const float* lw = lr_w + lane * 8;
  float4 la = *(const float4*)lw;
  float4 lb = *(const float4*)(lw + 4);
  float p = a.x * la.x + a.y * la.y + a.z * la.z + a.w * la.w +
            b.x * lb.x + b.y * lb.y + b.z * lb.z + b.w * lb.w;
#pragma unroll
  for (int m = 32; m > 0; m >>= 1) p += __shfl_xor(p, m, 64);
  if (lane == 0) eta[r] = 1.0f / (1.0f + expf(-(p + lr_b[0])));
}

// ---------------- gram kernel: per 16-step chunk, precompute -------------
//   KK[i][t] = k_i . k_t      (used for delayed-update u corrections)
//   KQ[i][t] = k_i . q_t      (u2 corrections; diag replaces the Qk allsum)
//   SC[t]    = sum_o g_o*(k_t_o + ln_b_o - v_t_o)   (the Sc allsum)
// Fully parallel (2048 blocks); these depend only on K,V,Q, not on W.
__global__ __launch_bounds__(256) void gram_kernel(
    const float* __restrict__ K, const float* __restrict__ V,
    const float* __restrict__ Q, const float* __restrict__ ln_g,
    const float* __restrict__ ln_b, float* __restrict__ G) {
  __shared__ __align__(16) float sK[16][64], sQ[16][64], sV[16][64];
  __shared__ float sg[64], sb[64];
  const int tid = threadIdx.x;
  const size_t row0 = (size_t)blockIdx.x * 16;
  ((float4*)sK)[tid] = ((const float4*)(K + row0 * BD))[tid];
  ((float4*)sQ)[tid] = ((const float4*)(Q + row0 * BD))[tid];
  ((float4*)sV)[tid] = ((const float4*)(V + row0 * BD))[tid];
  if (tid < 64) { sg[tid] = ln_g[tid]; sb[tid] = ln_b[tid]; }
  __syncthreads();
  const int i = tid >> 4, t = tid & 15;
  float kk = 0.f, kq = 0.f;
#pragma unroll
  for (int d = 0; d < 64; d += 4) {
    float4 a4 = *(const float4*)&sK[i][d];
    float4 b4 = *(const float4*)&sK[t][d];
    float4 c4 = *(const float4*)&sQ[t][d];
    kk += a4.x * b4.x + a4.y * b4.y + a4.z * b4.z + a4.w * b4.w;
    kq += a4.x * c4.x + a4.y * c4.y + a4.z * c4.z + a4.w * c4.w;
  }
  size_t gb = (size_t)blockIdx.x * GSTRIDE;
  G[gb + i * 16 + t] = kk;
  G[gb + 256 + i * 16 + t] = kq;
  if (tid < 16) {
    float sc = 0.f;
    for (int d = 0; d < 64; d++)
      sc += sg[d] * (sK[tid][d] + sb[d] - sV[tid][d]);
    G[gb + 512 + tid] = sc;
  }
}

// ---------------- sequential TTT scan: chunked delta-rule, 4 waves --------
// Round 8: r3 showed the kernel is dependency-latency-bound (8.7 cyc/instr;
// everything on one serial chain). Restructure via the chunked (look-ahead)
// form of the rank-1 recurrence, chunk = 16 steps:
//   u_t = U0[t] + sum_{i<t} coef_i*KK[i,t],  U0 = K_chunk @ W_chunkstart^T
//   p_t = P0[t] + sum_{i<=t} coef_i*KQ[i,t]
// Phase A (parallel): U0/P0 as wave-sliced partials; ONE LDS combine + 2
//   barriers per 16 steps (was 1 barrier+roundtrip PER step).
// Phase B (serial, barrier-free): per step only {5 allsums, scalar chain,
//   1 critical correction FMA}; Sc and q.k come precomputed from gram_kernel
//   (readlane). W-slice update + lazy corrections sit off the critical path.
__global__ __launch_bounds__(256, 1)
void ttt_seq_kernel(
    const float* __restrict__ Kin, const float* __restrict__ Vin,
    const float* __restrict__ Qin, const float* __restrict__ eta_in,
    const float* __restrict__ W0, const float* __restrict__ ln_g,
    const float* __restrict__ ln_b, float* __restrict__ Hout,
    const float* __restrict__ gram) {
  __shared__ __align__(16) float2 part2[16][4][64];  // 32 KB partials
  __shared__ __align__(16) float kls[16][64];        // 4 KB k rows (transposed access)
  __shared__ __align__(16) float qls[16][64];        // 4 KB q rows
  const int tid = threadIdx.x;
  const int lane = tid & 63;
  const int wvu = __builtin_amdgcn_readfirstlane(tid) >> 6;
  const int b = blockIdx.x;

  // W slice: w[4i+j] = W0[lane*BD + 16*wvu + 4i+j]
  float w[16];
  {
    const float4* w04 = (const float4*)(W0 + (size_t)lane * BD + wvu * 16);
#pragma unroll
    for (int i = 0; i < 4; i++) {
      float4 t4 = w04[i];
      w[4 * i] = t4.x; w[4 * i + 1] = t4.y; w[4 * i + 2] = t4.z; w[4 * i + 3] = t4.w;
    }
  }
  const float g = ln_g[lane];
  const float bet = ln_b[lane];
  const float a = g * g;
  const float A2 = wave_allsum(a);

  size_t base = (size_t)b * T * BD;   // advances BD per step
  size_t ebase = (size_t)b * T;

  // per-lane rows of the current chunk (reloaded in-place for chunk+1 during
  // phase B, period-16 ring -> zero extra registers)
  float krow[16], qrow[16], vrow[16];
#pragma unroll
  for (int r = 0; r < 16; r++) {
    krow[r] = Kin[base + r * BD + lane];
    qrow[r] = Qin[base + r * BD + lane];
    vrow[r] = Vin[base + r * BD + lane];
  }
  float ev  = eta_in[ebase + lane];
  float evn = eta_in[ebase + 64 + lane];

  float u2sv[4], qsv[4];  // deferred phase-2 state (4 owned steps per wave)

  for (int c64 = 0; c64 < 32; c64++) {
    size_t eoff = (size_t)(c64 + 2) * 64;
    if (eoff >= T) eoff = 0;
    float ev2 = eta_in[ebase + eoff + lane];

    for (int cc = 0; cc < 4; cc++) {
      // ---- gram loads for this chunk (consumed in phase B; phase A covers) --
      const size_t gb = (size_t)(b * 128 + c64 * 4 + cc) * GSTRIDE;
      float KKr[15], KQr[16];
#pragma unroll
      for (int t = 0; t < 15; t++) KKr[t] = gram[gb + t * 16 + lane];
#pragma unroll
      for (int t = 0; t < 16; t++) KQr[t] = gram[gb + 256 + t * 16 + lane];
      float SCv = gram[gb + 512 + lane];

      // ---- phase A: stage rows to LDS (all waves write identical values:
      // benign; each wave's own in-order DS writes make its reads correct) --
#pragma unroll
      for (int r = 0; r < 16; r++) {
        kls[r][lane] = krow[r];
        qls[r][lane] = qrow[r];
      }
      // 3-deep uniform-read pipeline (broadcast ds_read_b128, conflict-free)
      float4 kuf[3][4], quf[3][4];
#pragma unroll
      for (int r = 0; r < 3; r++) {
        const float4* kp = (const float4*)&kls[r][wvu * 16];
        const float4* qp = (const float4*)&qls[r][wvu * 16];
#pragma unroll
        for (int i = 0; i < 4; i++) { kuf[r][i] = kp[i]; quf[r][i] = qp[i]; }
      }
      float u0[16], p0[16];
#pragma unroll
      for (int r = 0; r < 16; r++) {
        const int bf = r % 3;
        float uu0 = 0.f, uu1 = 0.f, uu2 = 0.f, uu3 = 0.f;
        float pp0 = 0.f, pp1 = 0.f, pp2 = 0.f, pp3 = 0.f;
#pragma unroll
        for (int i = 0; i < 4; i++) {
          uu0 += kuf[bf][i].x * w[4 * i + 0];
          uu1 += kuf[bf][i].y * w[4 * i + 1];
          uu2 += kuf[bf][i].z * w[4 * i + 2];
          uu3 += kuf[bf][i].w * w[4 * i + 3];
          pp0 += quf[bf][i].x * w[4 * i + 0];
          pp1 += quf[bf][i].y * w[4 * i + 1];
          pp2 += quf[bf][i].z * w[4 * i + 2];
          pp3 += quf[bf][i].w * w[4 * i + 3];
        }
        part2[r][wvu][lane] = make_float2((uu0 + uu1) + (uu2 + uu3),
                                          (pp0 + pp1) + (pp2 + pp3));
        if (r < 13) {
          const float4* kp = (const float4*)&kls[r + 3][wvu * 16];
          const float4* qp = (const float4*)&qls[r + 3][wvu * 16];
#pragma unroll
          for (int i = 0; i < 4; i++) { kuf[bf][i] = kp[i]; quf[bf][i] = qp[i]; }
        }
      }

      lds_barrier();  // partials visible

      // combine partials (row 0 first: step 0 needs it immediately)
#pragma unroll
      for (int r = 0; r < 16; r++) {
        float2 pA = part2[r][0][lane];
        float2 pB = part2[r][1][lane];
        float2 pC = part2[r][2][lane];
        float2 pD = part2[r][3][lane];
        u0[r] = (pA.x + pB.x) + (pC.x + pD.x);
        p0[r] = (pA.y + pB.y) + (pC.y + pD.y);
      }

      // ---- phase B: 16 serial steps, no barriers ----
#pragma unroll
      for (int t = 0; t < 16; t++) {
        float u = u0[t];
        float kcur = krow[t], vcur = vrow[t], qcur = qrow[t];
        float ecur = __int_as_float(
            __builtin_amdgcn_readlane(__float_as_int(ev), cc * 16 + t));
        float c0 = g * (kcur + bet - vcur);

        float Su   = wave_allsum(u);
        float Suu  = wave_allsum(u * u);
        float Sau  = wave_allsum(a * u);
        float Sauu = wave_allsum(a * u * u);
        float Scu  = wave_allsum(c0 * u);
        float Sc   = __int_as_float(
            __builtin_amdgcn_readlane(__float_as_int(SCv), t));

        float mu = Su * (1.0f / 64);
        float var = Suu * (1.0f / 64) - mu * mu;
        float rstd = rsqrtf(var + 1e-6f);
        float xh = (u - mu) * rstd;
        float Axh   = rstd * (Sau - mu * A2);
        float Scxh  = rstd * (Scu - mu * Sc);
        float Saxh2 = rstd * rstd * (Sauu - 2.0f * mu * Sau + mu * mu * A2);
        float s1 = (2.0f / 64) * (Sc + Axh);
        float s2 = (2.0f / 64) * (Scxh + Saxh2);
        float dxh = (2.0f / 64) * (c0 + a * xh);
        float dldu = rstd * (dxh - s1 * (1.0f / 64) - xh * (s2 * (1.0f / 64)));
        float coef = -ecur * dldu;

        // critical correction first: u for step t+1
        if (t < 15)
          u0[t + 1] += coef * __int_as_float(
              __builtin_amdgcn_readlane(__float_as_int(KKr[t]), t + 1));
        // lazy corrections (off critical path)
#pragma unroll
        for (int s = t + 2; s < 16; s++)
          u0[s] += coef * __int_as_float(
              __builtin_amdgcn_readlane(__float_as_int(KKr[t]), s));
#pragma unroll
        for (int s = t; s < 16; s++)
          p0[s] += coef * __int_as_float(
              __builtin_amdgcn_readlane(__float_as_int(KQr[t]), s));

        // W-slice update via uniform LDS read of row t (off critical path;
        // next use of w is next chunk's phase A)
        {
          const float4* kp = (const float4*)&kls[t][wvu * 16];
#pragma unroll
          for (int i = 0; i < 4; i++) {
            float4 k4 = kp[i];
            w[4 * i + 0] += coef * k4.x;
            w[4 * i + 1] += coef * k4.y;
            w[4 * i + 2] += coef * k4.z;
            w[4 * i + 3] += coef * k4.w;
          }
        }

        if ((t & 3) == wvu) { u2sv[t >> 2] = p0[t]; qsv[t >> 2] = qcur; }

        // reload row t for the NEXT chunk (per-lane; 16 steps of cover)
        krow[t] = Kin[base + 16 * BD + lane];
        qrow[t] = Qin[base + 16 * BD + lane];
        vrow[t] = Vin[base + 16 * BD + lane];
        base += BD;
      }

      // ---- deferred phase-2 flush: each wave finalizes its 4 owned steps --
#pragma unroll
      for (int fi = 0; fi < 4; fi++) {
        float u2 = u2sv[fi];
        float Su2  = wave_allsum(u2);
        float Suu2 = wave_allsum(u2 * u2);
        float mu2 = Su2 * (1.0f / 64);
        float rstd2 = rsqrtf(Suu2 * (1.0f / 64) - mu2 * mu2 + 1e-6f);
        int tt = 4 * fi + wvu;
        Hout[base - (size_t)(16 - tt) * BD + lane] =
            qsv[fi] + (u2 - mu2) * rstd2 * g + bet;
      }

      // protect kls/qls/part2 (single-buffered) against next chunk's writes
      lds_barrier();
    }
    ev = evn; evn = ev2;
  }
}

// ---------------- out projection: z = H @ Wo + bo ----------------
__global__ __launch_bounds__(256) void outproj_kernel(
    const float* __restrict__ H, const float* __restrict__ Wo,
    const float* __restrict__ bo, float* __restrict__ out) {
  __shared__ __align__(16) float ht[16 * BD];  // 4 KB
  const int tid = threadIdx.x;
  const size_t row0 = (size_t)blockIdx.x * 16;
  ((float4*)ht)[tid] = ((const float4*)(H + row0 * BD))[tid];
  __syncthreads();
  float acc0[16], acc1[16];
#pragma unroll
  for (int r = 0; r < 16; r++) { acc0[r] = 0.f; acc1[r] = 0.f; }
  for (int kk = 0; kk < BD; kk++) {
    float w0 = Wo[kk * D + tid];
    float w1 = Wo[kk * D + tid + 256];
#pragma unroll
    for (int r = 0; r < 16; r++) {
      float hv = ht[r * BD + kk];
      acc0[r] += hv * w0;
      acc1[r] += hv * w1;
    }
  }
  float b0 = bo[tid], b1 = bo[tid + 256];
#pragma unroll
  for (int r = 0; r < 16; r++) {
    out[(row0 + r) * D + tid] = acc0[r] + b0;
    out[(row0 + r) * D + tid + 256] = acc1[r] + b1;
  }
}

extern "C" void kernel_launch(void* const* d_in, const int* in_sizes, int n_in,
                              void* d_out, int out_size, void* d_ws,
                              size_t ws_size, hipStream_t stream) {
  (void)in_sizes; (void)n_in; (void)out_size; (void)ws_size;
  const float* x    = (const float*)d_in[0];
  const float* Wk   = (const float*)d_in[1];
  const float* bk   = (const float*)d_in[2];
  const float* Wv   = (const float*)d_in[3];
  const float* bv   = (const float*)d_in[4];
  const float* Wq   = (const float*)d_in[5];
  const float* bq   = (const float*)d_in[6];
  const float* Wo   = (const float*)d_in[7];
  const float* bo   = (const float*)d_in[8];
  const float* ln_g = (const float*)d_in[9];
  const float* ln_b = (const float*)d_in[10];
  const float* lr_w = (const float*)d_in[11];
  const float* lr_b = (const float*)d_in[12];
  const float* W0   = (const float*)d_in[13];

  float* ws  = (float*)d_ws;
  float* Kb  = ws + OFF_K;
  float* Vb  = ws + OFF_V;
  float* Qb  = ws + OFF_Q;
  float* ETA = ws + OFF_ETA;
  float* Hb  = ws + OFF_H;
  float* out = (float*)d_out;
  float* GRAM = out;  // scratch inside d_out; overwritten later by outproj

  proj_kernel<<<BT / 16, 256, 0, stream>>>(x, Wk, bk, Wv, bv, Wq, bq, Kb, Vb, Qb);
  eta_kernel<<<BT / 4, 256, 0, stream>>>(x, lr_w, lr_b, ETA);
  gram_kernel<<<NCHUNK, 256, 0, stream>>>(Kb, Vb, Qb, ln_g, ln_b, GRAM);
  ttt_seq_kernel<<<NB, 256, 0, stream>>>(Kb, Vb, Qb, ETA, W0, ln_g, ln_b, Hb, GRAM);
  outproj_kernel<<<BT / 16, 256, 0, stream>>>(Hb, Wo, bo, out);
}